// Round 1
// baseline (3554.371 us; speedup 1.0000x reference)
//
#include <hip/hip_runtime.h>
#include <hip/hip_bf16.h>

#define N_NODES 100000
#define N_EDGES 1600000
#define E_TBL   200000
#define D       128
#define NREG    50000
#define P_MP    4
#define L_SUB   2
#define D_META  64
#define TM      64
#define SCALE_F 0.08838834764831845f   // 1/sqrt(128)

// ---------------- CSR build ----------------

__global__ void k_hist(const int* __restrict__ dst, int* __restrict__ cnt) {
    int e = blockIdx.x * blockDim.x + threadIdx.x;
    if (e < N_EDGES) atomicAdd(&cnt[dst[e]], 1);
}

__global__ __launch_bounds__(1024) void k_scan(const int* __restrict__ cnt,
                                               int* __restrict__ offs,
                                               int* __restrict__ cursor) {
    __shared__ int part[1024];
    int t = threadIdx.x;
    const int CH = (N_NODES + 1023) / 1024;          // 98
    int beg = t * CH;
    int end = min(beg + CH, N_NODES);
    int sum = 0;
    for (int i = beg; i < end; ++i) sum += cnt[i];
    part[t] = sum;
    __syncthreads();
    for (int o = 1; o < 1024; o <<= 1) {
        int v = (t >= o) ? part[t - o] : 0;
        __syncthreads();
        part[t] += v;
        __syncthreads();
    }
    int base = (t > 0) ? part[t - 1] : 0;
    for (int i = beg; i < end; ++i) {
        offs[i] = base;
        cursor[i] = base;
        base += cnt[i];
    }
    if (t == 1023) offs[N_NODES] = part[1023];
}

__global__ void k_scatter(const int* __restrict__ src, const int* __restrict__ dst,
                          int* __restrict__ cursor, int* __restrict__ ssrc) {
    int e = blockIdx.x * blockDim.x + threadIdx.x;
    if (e < N_EDGES) {
        int pos = atomicAdd(&cursor[dst[e]], 1);
        ssrc[pos] = src[e];
    }
}

// ---------------- gather x0 = E[eids] ----------------

__global__ void k_gather(const float* __restrict__ Etab, const int* __restrict__ eids,
                         float* __restrict__ x0) {
    int i = blockIdx.x * blockDim.x + threadIdx.x;   // over N_NODES*32 float4s
    int n = i >> 5, c4 = i & 31;
    if (n < N_NODES) {
        int r = eids[n];
        ((float4*)x0)[(size_t)n * 32 + c4] = ((const float4*)Etab)[(size_t)r * 32 + c4];
    }
}

// ---------------- SpMM: s[n] = sum_{e in csr(n)} x[ssrc[e]] / max(cnt,1) ----------------

__global__ __launch_bounds__(256) void k_spmm(const float* __restrict__ x,
                                              const int* __restrict__ offs,
                                              const int* __restrict__ cnt,
                                              const int* __restrict__ ssrc,
                                              float* __restrict__ s, int nrows) {
    int wv = (blockIdx.x * blockDim.x + threadIdx.x) >> 6;
    int lane = threadIdx.x & 63;
    if (wv >= nrows) return;
    int e0 = offs[wv], e1 = offs[wv + 1];
    float ax = 0.f, ay = 0.f;
    for (int e = e0; e < e1; ++e) {
        int sidx = ssrc[e];
        const float2 v = *(const float2*)(x + (size_t)sidx * D + lane * 2);
        ax += v.x; ay += v.y;
    }
    float inv = 1.0f / (float)max(cnt[wv], 1);
    float2 o; o.x = ax * inv; o.y = ay * inv;
    *(float2*)(s + (size_t)wv * D + lane * 2) = o;
}

// ---------------- fused GEMM: out = relu(s @ Wm + x @ Wr + b) ----------------
// block = 256 threads, tile = 64 rows x 128 cols; thread: 8 rows x 4 cols

__global__ __launch_bounds__(256) void k_gemm(const float* __restrict__ s,
                                              const float* __restrict__ x,
                                              const float* __restrict__ Wm,
                                              const float* __restrict__ Wr,
                                              const float* __restrict__ bias,
                                              float* __restrict__ out, int M) {
    __shared__ float As[TM][D];
    __shared__ float Ax[TM][D];
    int row0 = blockIdx.x * TM;
    int tid = threadIdx.x;

#pragma unroll
    for (int i = 0; i < 8; ++i) {                    // 64*128/4 float4s / 256 threads
        int flat = i * 256 + tid;
        int r = flat >> 5;
        int c4 = (flat & 31) * 4;
        int gr = row0 + r;
        float4 vs, vx;
        if (gr < M) {
            vs = *(const float4*)(s + (size_t)gr * D + c4);
            vx = *(const float4*)(x + (size_t)gr * D + c4);
        } else {
            vs = make_float4(0, 0, 0, 0);
            vx = vs;
        }
        *(float4*)&As[r][c4] = vs;
        *(float4*)&Ax[r][c4] = vx;
    }
    __syncthreads();

    int cg = (tid & 31) * 4;        // output col base
    int rg = (tid >> 5) * 8;        // output row base within tile
    float4 acc[8];
#pragma unroll
    for (int i = 0; i < 8; ++i) acc[i] = make_float4(0, 0, 0, 0);

    for (int k = 0; k < D; k += 4) {
        float4 wm0 = *(const float4*)(Wm + (size_t)(k + 0) * D + cg);
        float4 wm1 = *(const float4*)(Wm + (size_t)(k + 1) * D + cg);
        float4 wm2 = *(const float4*)(Wm + (size_t)(k + 2) * D + cg);
        float4 wm3 = *(const float4*)(Wm + (size_t)(k + 3) * D + cg);
        float4 wr0 = *(const float4*)(Wr + (size_t)(k + 0) * D + cg);
        float4 wr1 = *(const float4*)(Wr + (size_t)(k + 1) * D + cg);
        float4 wr2 = *(const float4*)(Wr + (size_t)(k + 2) * D + cg);
        float4 wr3 = *(const float4*)(Wr + (size_t)(k + 3) * D + cg);
#pragma unroll
        for (int i = 0; i < 8; ++i) {
            float4 a = *(const float4*)&As[rg + i][k];
            float4 c = *(const float4*)&Ax[rg + i][k];
            acc[i].x += a.x * wm0.x + a.y * wm1.x + a.z * wm2.x + a.w * wm3.x
                      + c.x * wr0.x + c.y * wr1.x + c.z * wr2.x + c.w * wr3.x;
            acc[i].y += a.x * wm0.y + a.y * wm1.y + a.z * wm2.y + a.w * wm3.y
                      + c.x * wr0.y + c.y * wr1.y + c.z * wr2.y + c.w * wr3.y;
            acc[i].z += a.x * wm0.z + a.y * wm1.z + a.z * wm2.z + a.w * wm3.z
                      + c.x * wr0.z + c.y * wr1.z + c.z * wr2.z + c.w * wr3.z;
            acc[i].w += a.x * wm0.w + a.y * wm1.w + a.z * wm2.w + a.w * wm3.w
                      + c.x * wr0.w + c.y * wr1.w + c.z * wr2.w + c.w * wr3.w;
        }
    }

    float4 bv = *(const float4*)(bias + cg);
#pragma unroll
    for (int i = 0; i < 8; ++i) {
        int gr = row0 + rg + i;
        if (gr < M) {
            float4 o;
            o.x = fmaxf(acc[i].x + bv.x, 0.f);
            o.y = fmaxf(acc[i].y + bv.y, 0.f);
            o.z = fmaxf(acc[i].z + bv.z, 0.f);
            o.w = fmaxf(acc[i].w + bv.w, 0.f);
            *(float4*)(out + (size_t)gr * D + cg) = o;
        }
    }
}

// ---------------- query = meta @ Wq + bq ----------------

__global__ void k_query(const float* __restrict__ meta, const float* __restrict__ Wq,
                        const float* __restrict__ bq, float* __restrict__ query) {
    int t = blockIdx.x * blockDim.x + threadIdx.x;
    if (t < P_MP * D) {
        int p = t >> 7, c = t & 127;
        float acc = bq[c];
        for (int k = 0; k < D_META; ++k) acc += meta[p * D_META + k] * Wq[k * D + c];
        query[t] = acc;
    }
}

// ---------------- final: per-node softmax over metapaths ----------------

__global__ __launch_bounds__(256) void k_final(const float* __restrict__ emb,
                                               const float* __restrict__ query,
                                               float* __restrict__ out) {
    int wv = (blockIdx.x * blockDim.x + threadIdx.x) >> 6;
    int lane = threadIdx.x & 63;
    if (wv >= NREG) return;
    float2 e[4];
    float sc[4];
#pragma unroll
    for (int p = 0; p < 4; ++p) {
        e[p] = *(const float2*)(emb + ((size_t)p * NREG + wv) * D + lane * 2);
        float2 q = *(const float2*)(query + p * D + lane * 2);
        float d = e[p].x * q.x + e[p].y * q.y;
#pragma unroll
        for (int o = 32; o > 0; o >>= 1) d += __shfl_xor(d, o, 64);
        sc[p] = d * SCALE_F;
    }
    float mx = fmaxf(fmaxf(sc[0], sc[1]), fmaxf(sc[2], sc[3]));
    float w[4], sum = 0.f;
#pragma unroll
    for (int p = 0; p < 4; ++p) { w[p] = __expf(sc[p] - mx); sum += w[p]; }
    float inv = 1.f / sum;
    float ox = 0.f, oy = 0.f;
#pragma unroll
    for (int p = 0; p < 4; ++p) { ox += w[p] * inv * e[p].x; oy += w[p] * inv * e[p].y; }
    float2 o; o.x = ox; o.y = oy;
    *(float2*)(out + (size_t)wv * D + lane * 2) = o;
}

// ---------------- launch ----------------

extern "C" void kernel_launch(void* const* d_in, const int* in_sizes, int n_in,
                              void* d_out, int out_size, void* d_ws, size_t ws_size,
                              hipStream_t stream) {
    const float* Etab  = (const float*)d_in[0];
    const float* meta  = (const float*)d_in[1];
    const float* Wroot = (const float*)d_in[2];   // [4][2][128][128]
    const float* Wrel  = (const float*)d_in[3];   // [4][2][128][128]
    const float* bvec  = (const float*)d_in[4];   // [4][2][128]
    const float* Wq    = (const float*)d_in[5];   // [64][128]
    const float* bq    = (const float*)d_in[6];   // [128]
    const int* edge_index = (const int*)d_in[7];  // [4][2][1600000]
    const int* eids       = (const int*)d_in[8];  // [4][100000]
    float* out = (float*)d_out;

    char* w = (char*)d_ws;
    float* x0   = (float*)w;  w += (size_t)N_NODES * D * 4;      // 51.2 MB
    float* h1   = (float*)w;  w += (size_t)N_NODES * D * 4;      // 51.2 MB
    float* sbuf = (float*)w;  w += (size_t)N_NODES * D * 4;      // 51.2 MB
    float* emb  = (float*)w;  w += (size_t)P_MP * NREG * D * 4;  // 102.4 MB
    float* query= (float*)w;  w += 512 * 4;
    int* cnt    = (int*)w;    w += (size_t)N_NODES * 4;
    int* offs   = (int*)w;    w += (size_t)(N_NODES + 1) * 4;
    int* cursor = (int*)w;    w += (size_t)N_NODES * 4;
    int* ssrc   = (int*)w;    w += (size_t)N_EDGES * 4;

    for (int p = 0; p < P_MP; ++p) {
        const int* src = edge_index + (size_t)p * 2 * N_EDGES;
        const int* dst = src + N_EDGES;
        const int* eid = eids + (size_t)p * N_NODES;

        hipMemsetAsync(cnt, 0, (size_t)N_NODES * 4, stream);
        k_hist<<<(N_EDGES + 255) / 256, 256, 0, stream>>>(dst, cnt);
        k_scan<<<1, 1024, 0, stream>>>(cnt, offs, cursor);
        k_scatter<<<(N_EDGES + 255) / 256, 256, 0, stream>>>(src, dst, cursor, ssrc);
        k_gather<<<(N_NODES * 32 + 255) / 256, 256, 0, stream>>>(Etab, eid, x0);

        // layer 1 (M = N_NODES)
        k_spmm<<<(N_NODES * 64 + 255) / 256, 256, 0, stream>>>(x0, offs, cnt, ssrc, sbuf, N_NODES);
        {
            const float* Wm = Wrel  + ((size_t)p * L_SUB + 0) * D * D;
            const float* Wr = Wroot + ((size_t)p * L_SUB + 0) * D * D;
            const float* bb = bvec  + ((size_t)p * L_SUB + 0) * D;
            k_gemm<<<(N_NODES + TM - 1) / TM, 256, 0, stream>>>(sbuf, x0, Wm, Wr, bb, h1, N_NODES);
        }
        // layer 2 (only rows < NREG are ever consumed)
        k_spmm<<<(NREG * 64 + 255) / 256, 256, 0, stream>>>(h1, offs, cnt, ssrc, sbuf, NREG);
        {
            const float* Wm = Wrel  + ((size_t)p * L_SUB + 1) * D * D;
            const float* Wr = Wroot + ((size_t)p * L_SUB + 1) * D * D;
            const float* bb = bvec  + ((size_t)p * L_SUB + 1) * D;
            k_gemm<<<(NREG + TM - 1) / TM, 256, 0, stream>>>(sbuf, h1, Wm, Wr, bb,
                                                             emb + (size_t)p * NREG * D, NREG);
        }
    }

    k_query<<<2, 256, 0, stream>>>(meta, Wq, bq, query);
    k_final<<<(NREG * 64 + 255) / 256, 256, 0, stream>>>(emb, query, out);
}

// Round 2
// 2673.090 us; speedup vs baseline: 1.3297x; 1.3297x over previous
//
#include <hip/hip_runtime.h>
#include <hip/hip_bf16.h>

#define N_NODES 100000
#define N_EDGES 1600000
#define E_TBL   200000
#define D       128
#define NREG    50000
#define P_MP    4
#define L_SUB   2
#define D_META  64
#define TM      64
#define SCALE_F 0.08838834764831845f   // 1/sqrt(128)

#define SCAN_CHUNK  512
#define SCAN_BLOCKS ((N_NODES + SCAN_CHUNK - 1) / SCAN_CHUNK)   // 196

// ---------------- CSR build ----------------

__global__ void k_hist(const int* __restrict__ dst, int* __restrict__ cnt) {
    int e = blockIdx.x * blockDim.x + threadIdx.x;
    if (e < N_EDGES) atomicAdd(&cnt[dst[e]], 1);
}

// pass 1: per-block partial sums of cnt (196 blocks x 256 thr, 2 elems/thr)
__global__ __launch_bounds__(256) void k_bsum(const int* __restrict__ cnt,
                                              int* __restrict__ bsum) {
    __shared__ int red[256];
    int b = blockIdx.x, t = threadIdx.x;
    int base = b * SCAN_CHUNK + t;
    int v = 0;
    if (base < N_NODES) v += cnt[base];
    if (base + 256 < N_NODES) v += cnt[base + 256];
    red[t] = v;
    __syncthreads();
    for (int o = 128; o > 0; o >>= 1) {
        if (t < o) red[t] += red[t + o];
        __syncthreads();
    }
    if (t == 0) bsum[b] = red[0];
}

// pass 2: exclusive scan of the 196 block sums (1 block)
__global__ __launch_bounds__(256) void k_scan_bsum(const int* __restrict__ bsum,
                                                   int* __restrict__ ebsum) {
    __shared__ int sh[256];
    int t = threadIdx.x;
    int v = (t < SCAN_BLOCKS) ? bsum[t] : 0;
    sh[t] = v;
    __syncthreads();
    for (int o = 1; o < 256; o <<= 1) {
        int u = (t >= o) ? sh[t - o] : 0;
        __syncthreads();
        sh[t] += u;
        __syncthreads();
    }
    if (t < SCAN_BLOCKS) ebsum[t] = sh[t] - v;   // exclusive
}

// pass 3: block-local exclusive scan + global offset, write offs & cursor
__global__ __launch_bounds__(256) void k_offs(const int* __restrict__ cnt,
                                              const int* __restrict__ ebsum,
                                              int* __restrict__ offs,
                                              int* __restrict__ cursor) {
    __shared__ int pair[256];
    int b = blockIdx.x, t = threadIdx.x;
    int i0 = b * SCAN_CHUNK + 2 * t;
    int i1 = i0 + 1;
    int c0 = (i0 < N_NODES) ? cnt[i0] : 0;
    int c1 = (i1 < N_NODES) ? cnt[i1] : 0;
    int ps = c0 + c1;
    pair[t] = ps;
    __syncthreads();
    for (int o = 1; o < 256; o <<= 1) {
        int u = (t >= o) ? pair[t - o] : 0;
        __syncthreads();
        pair[t] += u;
        __syncthreads();
    }
    int off0 = ebsum[b] + pair[t] - ps;          // exclusive prefix for i0
    if (i0 < N_NODES) { offs[i0] = off0; cursor[i0] = off0; }
    if (i1 < N_NODES) { offs[i1] = off0 + c0; cursor[i1] = off0 + c0; }
    if (b == 0 && t == 0) offs[N_NODES] = N_EDGES;   // total is a constant
}

__global__ void k_scatter(const int* __restrict__ src, const int* __restrict__ dst,
                          int* __restrict__ cursor, int* __restrict__ ssrc) {
    int e = blockIdx.x * blockDim.x + threadIdx.x;
    if (e < N_EDGES) {
        int pos = atomicAdd(&cursor[dst[e]], 1);
        ssrc[pos] = src[e];
    }
}

// ---------------- gather x0 = E[eids] ----------------

__global__ void k_gather(const float* __restrict__ Etab, const int* __restrict__ eids,
                         float* __restrict__ x0) {
    int i = blockIdx.x * blockDim.x + threadIdx.x;   // over N_NODES*32 float4s
    int n = i >> 5, c4 = i & 31;
    if (n < N_NODES) {
        int r = eids[n];
        ((float4*)x0)[(size_t)n * 32 + c4] = ((const float4*)Etab)[(size_t)r * 32 + c4];
    }
}

// ---------------- SpMM: s[n] = sum_{e in csr(n)} x[ssrc[e]] / max(cnt,1) ----------------

__global__ __launch_bounds__(256) void k_spmm(const float* __restrict__ x,
                                              const int* __restrict__ offs,
                                              const int* __restrict__ cnt,
                                              const int* __restrict__ ssrc,
                                              float* __restrict__ s, int nrows) {
    int wv = (blockIdx.x * blockDim.x + threadIdx.x) >> 6;
    int lane = threadIdx.x & 63;
    if (wv >= nrows) return;
    int e0 = offs[wv], e1 = offs[wv + 1];
    float ax = 0.f, ay = 0.f;
    for (int e = e0; e < e1; ++e) {
        int sidx = ssrc[e];
        const float2 v = *(const float2*)(x + (size_t)sidx * D + lane * 2);
        ax += v.x; ay += v.y;
    }
    float inv = 1.0f / (float)max(cnt[wv], 1);
    float2 o; o.x = ax * inv; o.y = ay * inv;
    *(float2*)(s + (size_t)wv * D + lane * 2) = o;
}

// ---------------- fused GEMM: out = relu(s @ Wm + x @ Wr + b) ----------------
// block = 256 threads, tile = 64 rows x 128 cols; thread: 8 rows x 4 cols

__global__ __launch_bounds__(256) void k_gemm(const float* __restrict__ s,
                                              const float* __restrict__ x,
                                              const float* __restrict__ Wm,
                                              const float* __restrict__ Wr,
                                              const float* __restrict__ bias,
                                              float* __restrict__ out, int M) {
    __shared__ float As[TM][D];
    __shared__ float Ax[TM][D];
    int row0 = blockIdx.x * TM;
    int tid = threadIdx.x;

#pragma unroll
    for (int i = 0; i < 8; ++i) {                    // 64*128/4 float4s / 256 threads
        int flat = i * 256 + tid;
        int r = flat >> 5;
        int c4 = (flat & 31) * 4;
        int gr = row0 + r;
        float4 vs, vx;
        if (gr < M) {
            vs = *(const float4*)(s + (size_t)gr * D + c4);
            vx = *(const float4*)(x + (size_t)gr * D + c4);
        } else {
            vs = make_float4(0, 0, 0, 0);
            vx = vs;
        }
        *(float4*)&As[r][c4] = vs;
        *(float4*)&Ax[r][c4] = vx;
    }
    __syncthreads();

    int cg = (tid & 31) * 4;        // output col base
    int rg = (tid >> 5) * 8;        // output row base within tile
    float4 acc[8];
#pragma unroll
    for (int i = 0; i < 8; ++i) acc[i] = make_float4(0, 0, 0, 0);

    for (int k = 0; k < D; k += 4) {
        float4 wm0 = *(const float4*)(Wm + (size_t)(k + 0) * D + cg);
        float4 wm1 = *(const float4*)(Wm + (size_t)(k + 1) * D + cg);
        float4 wm2 = *(const float4*)(Wm + (size_t)(k + 2) * D + cg);
        float4 wm3 = *(const float4*)(Wm + (size_t)(k + 3) * D + cg);
        float4 wr0 = *(const float4*)(Wr + (size_t)(k + 0) * D + cg);
        float4 wr1 = *(const float4*)(Wr + (size_t)(k + 1) * D + cg);
        float4 wr2 = *(const float4*)(Wr + (size_t)(k + 2) * D + cg);
        float4 wr3 = *(const float4*)(Wr + (size_t)(k + 3) * D + cg);
#pragma unroll
        for (int i = 0; i < 8; ++i) {
            float4 a = *(const float4*)&As[rg + i][k];
            float4 c = *(const float4*)&Ax[rg + i][k];
            acc[i].x += a.x * wm0.x + a.y * wm1.x + a.z * wm2.x + a.w * wm3.x
                      + c.x * wr0.x + c.y * wr1.x + c.z * wr2.x + c.w * wr3.x;
            acc[i].y += a.x * wm0.y + a.y * wm1.y + a.z * wm2.y + a.w * wm3.y
                      + c.x * wr0.y + c.y * wr1.y + c.z * wr2.y + c.w * wr3.y;
            acc[i].z += a.x * wm0.z + a.y * wm1.z + a.z * wm2.z + a.w * wm3.z
                      + c.x * wr0.z + c.y * wr1.z + c.z * wr2.z + c.w * wr3.z;
            acc[i].w += a.x * wm0.w + a.y * wm1.w + a.z * wm2.w + a.w * wm3.w
                      + c.x * wr0.w + c.y * wr1.w + c.z * wr2.w + c.w * wr3.w;
        }
    }

    float4 bv = *(const float4*)(bias + cg);
#pragma unroll
    for (int i = 0; i < 8; ++i) {
        int gr = row0 + rg + i;
        if (gr < M) {
            float4 o;
            o.x = fmaxf(acc[i].x + bv.x, 0.f);
            o.y = fmaxf(acc[i].y + bv.y, 0.f);
            o.z = fmaxf(acc[i].z + bv.z, 0.f);
            o.w = fmaxf(acc[i].w + bv.w, 0.f);
            *(float4*)(out + (size_t)gr * D + cg) = o;
        }
    }
}

// ---------------- query = meta @ Wq + bq ----------------

__global__ void k_query(const float* __restrict__ meta, const float* __restrict__ Wq,
                        const float* __restrict__ bq, float* __restrict__ query) {
    int t = blockIdx.x * blockDim.x + threadIdx.x;
    if (t < P_MP * D) {
        int p = t >> 7, c = t & 127;
        float acc = bq[c];
        for (int k = 0; k < D_META; ++k) acc += meta[p * D_META + k] * Wq[k * D + c];
        query[t] = acc;
    }
}

// ---------------- final: per-node softmax over metapaths ----------------

__global__ __launch_bounds__(256) void k_final(const float* __restrict__ emb,
                                               const float* __restrict__ query,
                                               float* __restrict__ out) {
    int wv = (blockIdx.x * blockDim.x + threadIdx.x) >> 6;
    int lane = threadIdx.x & 63;
    if (wv >= NREG) return;
    float2 e[4];
    float sc[4];
#pragma unroll
    for (int p = 0; p < 4; ++p) {
        e[p] = *(const float2*)(emb + ((size_t)p * NREG + wv) * D + lane * 2);
        float2 q = *(const float2*)(query + p * D + lane * 2);
        float d = e[p].x * q.x + e[p].y * q.y;
#pragma unroll
        for (int o = 32; o > 0; o >>= 1) d += __shfl_xor(d, o, 64);
        sc[p] = d * SCALE_F;
    }
    float mx = fmaxf(fmaxf(sc[0], sc[1]), fmaxf(sc[2], sc[3]));
    float w[4], sum = 0.f;
#pragma unroll
    for (int p = 0; p < 4; ++p) { w[p] = __expf(sc[p] - mx); sum += w[p]; }
    float inv = 1.f / sum;
    float ox = 0.f, oy = 0.f;
#pragma unroll
    for (int p = 0; p < 4; ++p) { ox += w[p] * inv * e[p].x; oy += w[p] * inv * e[p].y; }
    float2 o; o.x = ox; o.y = oy;
    *(float2*)(out + (size_t)wv * D + lane * 2) = o;
}

// ---------------- launch ----------------

extern "C" void kernel_launch(void* const* d_in, const int* in_sizes, int n_in,
                              void* d_out, int out_size, void* d_ws, size_t ws_size,
                              hipStream_t stream) {
    const float* Etab  = (const float*)d_in[0];
    const float* meta  = (const float*)d_in[1];
    const float* Wroot = (const float*)d_in[2];   // [4][2][128][128]
    const float* Wrel  = (const float*)d_in[3];   // [4][2][128][128]
    const float* bvec  = (const float*)d_in[4];   // [4][2][128]
    const float* Wq    = (const float*)d_in[5];   // [64][128]
    const float* bq    = (const float*)d_in[6];   // [128]
    const int* edge_index = (const int*)d_in[7];  // [4][2][1600000]
    const int* eids       = (const int*)d_in[8];  // [4][100000]
    float* out = (float*)d_out;

    char* w = (char*)d_ws;
    float* x0   = (float*)w;  w += (size_t)N_NODES * D * 4;      // 51.2 MB
    float* h1   = (float*)w;  w += (size_t)N_NODES * D * 4;      // 51.2 MB
    float* sbuf = (float*)w;  w += (size_t)N_NODES * D * 4;      // 51.2 MB
    float* emb  = (float*)w;  w += (size_t)P_MP * NREG * D * 4;  // 102.4 MB
    float* query= (float*)w;  w += 512 * 4;
    int* cnt    = (int*)w;    w += (size_t)N_NODES * 4;
    int* offs   = (int*)w;    w += (size_t)(N_NODES + 1) * 4;
    int* cursor = (int*)w;    w += (size_t)N_NODES * 4;
    int* ssrc   = (int*)w;    w += (size_t)N_EDGES * 4;
    int* bsum   = (int*)w;    w += (size_t)SCAN_BLOCKS * 4;
    int* ebsum  = (int*)w;    w += (size_t)SCAN_BLOCKS * 4;

    for (int p = 0; p < P_MP; ++p) {
        const int* src = edge_index + (size_t)p * 2 * N_EDGES;
        const int* dst = src + N_EDGES;
        const int* eid = eids + (size_t)p * N_NODES;

        hipMemsetAsync(cnt, 0, (size_t)N_NODES * 4, stream);
        k_hist<<<(N_EDGES + 255) / 256, 256, 0, stream>>>(dst, cnt);
        k_bsum<<<SCAN_BLOCKS, 256, 0, stream>>>(cnt, bsum);
        k_scan_bsum<<<1, 256, 0, stream>>>(bsum, ebsum);
        k_offs<<<SCAN_BLOCKS, 256, 0, stream>>>(cnt, ebsum, offs, cursor);
        k_scatter<<<(N_EDGES + 255) / 256, 256, 0, stream>>>(src, dst, cursor, ssrc);
        k_gather<<<(N_NODES * 32 + 255) / 256, 256, 0, stream>>>(Etab, eid, x0);

        // layer 1 (M = N_NODES)
        k_spmm<<<(N_NODES * 64 + 255) / 256, 256, 0, stream>>>(x0, offs, cnt, ssrc, sbuf, N_NODES);
        {
            const float* Wm = Wrel  + ((size_t)p * L_SUB + 0) * D * D;
            const float* Wr = Wroot + ((size_t)p * L_SUB + 0) * D * D;
            const float* bb = bvec  + ((size_t)p * L_SUB + 0) * D;
            k_gemm<<<(N_NODES + TM - 1) / TM, 256, 0, stream>>>(sbuf, x0, Wm, Wr, bb, h1, N_NODES);
        }
        // layer 2 (only rows < NREG are ever consumed)
        k_spmm<<<(NREG * 64 + 255) / 256, 256, 0, stream>>>(h1, offs, cnt, ssrc, sbuf, NREG);
        {
            const float* Wm = Wrel  + ((size_t)p * L_SUB + 1) * D * D;
            const float* Wr = Wroot + ((size_t)p * L_SUB + 1) * D * D;
            const float* bb = bvec  + ((size_t)p * L_SUB + 1) * D;
            k_gemm<<<(NREG + TM - 1) / TM, 256, 0, stream>>>(sbuf, h1, Wm, Wr, bb,
                                                             emb + (size_t)p * NREG * D, NREG);
        }
    }

    k_query<<<2, 256, 0, stream>>>(meta, Wq, bq, query);
    k_final<<<(NREG * 64 + 255) / 256, 256, 0, stream>>>(emb, query, out);
}

// Round 3
// 2534.955 us; speedup vs baseline: 1.4021x; 1.0545x over previous
//
#include <hip/hip_runtime.h>
#include <hip/hip_bf16.h>

#define N_NODES 100000
#define N_EDGES 1600000
#define E_TBL   200000
#define D       128
#define NREG    50000
#define P_MP    4
#define L_SUB   2
#define D_META  64
#define TM      64
#define SCALE_F 0.08838834764831845f   // 1/sqrt(128)

#define SCAN_CHUNK  512
#define SCAN_BLOCKS ((N_NODES + SCAN_CHUNK - 1) / SCAN_CHUNK)   // 196

// ---------------- bf16 helpers (storage-only precision reduction) ----------------

__device__ __forceinline__ float bf2f(unsigned int u16) {
    union { unsigned int i; float f; } v;
    v.i = u16 << 16;
    return v.f;
}
__device__ __forceinline__ unsigned int f2bf(float f) {
    union { float f; unsigned int i; } v;
    v.f = f;
    // round-to-nearest-even
    return (v.i + 0x7fffu + ((v.i >> 16) & 1u)) >> 16;
}

// ---------------- CSR build ----------------

__global__ void k_hist(const int* __restrict__ dst, int* __restrict__ cnt) {
    int e = blockIdx.x * blockDim.x + threadIdx.x;
    if (e < N_EDGES) atomicAdd(&cnt[dst[e]], 1);
}

__global__ __launch_bounds__(256) void k_bsum(const int* __restrict__ cnt,
                                              int* __restrict__ bsum) {
    __shared__ int red[256];
    int b = blockIdx.x, t = threadIdx.x;
    int base = b * SCAN_CHUNK + t;
    int v = 0;
    if (base < N_NODES) v += cnt[base];
    if (base + 256 < N_NODES) v += cnt[base + 256];
    red[t] = v;
    __syncthreads();
    for (int o = 128; o > 0; o >>= 1) {
        if (t < o) red[t] += red[t + o];
        __syncthreads();
    }
    if (t == 0) bsum[b] = red[0];
}

__global__ __launch_bounds__(256) void k_scan_bsum(const int* __restrict__ bsum,
                                                   int* __restrict__ ebsum) {
    __shared__ int sh[256];
    int t = threadIdx.x;
    int v = (t < SCAN_BLOCKS) ? bsum[t] : 0;
    sh[t] = v;
    __syncthreads();
    for (int o = 1; o < 256; o <<= 1) {
        int u = (t >= o) ? sh[t - o] : 0;
        __syncthreads();
        sh[t] += u;
        __syncthreads();
    }
    if (t < SCAN_BLOCKS) ebsum[t] = sh[t] - v;   // exclusive
}

__global__ __launch_bounds__(256) void k_offs(const int* __restrict__ cnt,
                                              const int* __restrict__ ebsum,
                                              int* __restrict__ offs,
                                              int* __restrict__ cursor) {
    __shared__ int pair[256];
    int b = blockIdx.x, t = threadIdx.x;
    int i0 = b * SCAN_CHUNK + 2 * t;
    int i1 = i0 + 1;
    int c0 = (i0 < N_NODES) ? cnt[i0] : 0;
    int c1 = (i1 < N_NODES) ? cnt[i1] : 0;
    int ps = c0 + c1;
    pair[t] = ps;
    __syncthreads();
    for (int o = 1; o < 256; o <<= 1) {
        int u = (t >= o) ? pair[t - o] : 0;
        __syncthreads();
        pair[t] += u;
        __syncthreads();
    }
    int off0 = ebsum[b] + pair[t] - ps;
    if (i0 < N_NODES) { offs[i0] = off0; cursor[i0] = off0; }
    if (i1 < N_NODES) { offs[i1] = off0 + c0; cursor[i1] = off0 + c0; }
    if (b == 0 && t == 0) offs[N_NODES] = N_EDGES;
}

__global__ void k_scatter(const int* __restrict__ src, const int* __restrict__ dst,
                          int* __restrict__ cursor, int* __restrict__ ssrc) {
    int e = blockIdx.x * blockDim.x + threadIdx.x;
    if (e < N_EDGES) {
        int pos = atomicAdd(&cursor[dst[e]], 1);
        ssrc[pos] = src[e];
    }
}

// ---------------- gather x0 = bf16(E[eids]) ----------------

__global__ void k_gather(const float* __restrict__ Etab, const int* __restrict__ eids,
                         unsigned short* __restrict__ x0) {
    int i = blockIdx.x * blockDim.x + threadIdx.x;   // N_NODES * 16 (8 cols each)
    int n = i >> 4, g = i & 15;
    if (n >= N_NODES) return;
    int r = eids[n];
    const float4* srcp = (const float4*)(Etab + (size_t)r * D + g * 8);
    float4 a = srcp[0], b = srcp[1];
    uint4 o;
    o.x = f2bf(a.x) | (f2bf(a.y) << 16);
    o.y = f2bf(a.z) | (f2bf(a.w) << 16);
    o.z = f2bf(b.x) | (f2bf(b.y) << 16);
    o.w = f2bf(b.z) | (f2bf(b.w) << 16);
    *(uint4*)(x0 + (size_t)n * D + g * 8) = o;
}

// ---------------- SpMM (bf16 rows, f32 accumulate, bf16 out) ----------------

__global__ __launch_bounds__(256) void k_spmm(const unsigned short* __restrict__ x,
                                              const int* __restrict__ offs,
                                              const int* __restrict__ cnt,
                                              const int* __restrict__ ssrc,
                                              unsigned short* __restrict__ s, int nrows) {
    int wv = (blockIdx.x * blockDim.x + threadIdx.x) >> 6;
    int lane = threadIdx.x & 63;
    if (wv >= nrows) return;
    int e0 = offs[wv], e1 = offs[wv + 1];
    const unsigned int* xb = (const unsigned int*)x;   // 2 bf16 per uint, 64 per row
    float ax = 0.f, ay = 0.f;
    for (int e = e0; e < e1; ++e) {
        int sidx = ssrc[e];
        unsigned int v = xb[(size_t)sidx * 64 + lane];
        ax += bf2f(v & 0xffffu);
        ay += bf2f(v >> 16);
    }
    float inv = 1.0f / (float)max(cnt[wv], 1);
    unsigned int o = f2bf(ax * inv) | (f2bf(ay * inv) << 16);
    ((unsigned int*)s)[(size_t)wv * 64 + lane] = o;
}

// ---------------- fused GEMM: out = relu(s @ Wm + x @ Wr + b), f32 math ----------------
// inputs s,x are bf16; LDS holds f32; OUT_BF16 picks output packing

template <bool OUT_BF16>
__global__ __launch_bounds__(256) void k_gemm(const unsigned short* __restrict__ s,
                                              const unsigned short* __restrict__ x,
                                              const float* __restrict__ Wm,
                                              const float* __restrict__ Wr,
                                              const float* __restrict__ bias,
                                              void* __restrict__ outv, int M) {
    __shared__ float As[TM][D];
    __shared__ float Ax[TM][D];
    int row0 = blockIdx.x * TM;
    int tid = threadIdx.x;

#pragma unroll
    for (int i = 0; i < 4; ++i) {                    // 64*128 bf16 = 1024 uint4 per matrix
        int flat = i * 256 + tid;
        int r = flat >> 4;
        int c8 = (flat & 15) * 8;
        int gr = row0 + r;
        uint4 vs = make_uint4(0, 0, 0, 0), vx = vs;
        if (gr < M) {
            vs = *(const uint4*)(s + (size_t)gr * D + c8);
            vx = *(const uint4*)(x + (size_t)gr * D + c8);
        }
        As[r][c8 + 0] = bf2f(vs.x & 0xffffu); As[r][c8 + 1] = bf2f(vs.x >> 16);
        As[r][c8 + 2] = bf2f(vs.y & 0xffffu); As[r][c8 + 3] = bf2f(vs.y >> 16);
        As[r][c8 + 4] = bf2f(vs.z & 0xffffu); As[r][c8 + 5] = bf2f(vs.z >> 16);
        As[r][c8 + 6] = bf2f(vs.w & 0xffffu); As[r][c8 + 7] = bf2f(vs.w >> 16);
        Ax[r][c8 + 0] = bf2f(vx.x & 0xffffu); Ax[r][c8 + 1] = bf2f(vx.x >> 16);
        Ax[r][c8 + 2] = bf2f(vx.y & 0xffffu); Ax[r][c8 + 3] = bf2f(vx.y >> 16);
        Ax[r][c8 + 4] = bf2f(vx.z & 0xffffu); Ax[r][c8 + 5] = bf2f(vx.z >> 16);
        Ax[r][c8 + 6] = bf2f(vx.w & 0xffffu); Ax[r][c8 + 7] = bf2f(vx.w >> 16);
    }
    __syncthreads();

    int cg = (tid & 31) * 4;
    int rg = (tid >> 5) * 8;
    float4 acc[8];
#pragma unroll
    for (int i = 0; i < 8; ++i) acc[i] = make_float4(0, 0, 0, 0);

    for (int k = 0; k < D; k += 4) {
        float4 wm0 = *(const float4*)(Wm + (size_t)(k + 0) * D + cg);
        float4 wm1 = *(const float4*)(Wm + (size_t)(k + 1) * D + cg);
        float4 wm2 = *(const float4*)(Wm + (size_t)(k + 2) * D + cg);
        float4 wm3 = *(const float4*)(Wm + (size_t)(k + 3) * D + cg);
        float4 wr0 = *(const float4*)(Wr + (size_t)(k + 0) * D + cg);
        float4 wr1 = *(const float4*)(Wr + (size_t)(k + 1) * D + cg);
        float4 wr2 = *(const float4*)(Wr + (size_t)(k + 2) * D + cg);
        float4 wr3 = *(const float4*)(Wr + (size_t)(k + 3) * D + cg);
#pragma unroll
        for (int i = 0; i < 8; ++i) {
            float4 a = *(const float4*)&As[rg + i][k];
            float4 c = *(const float4*)&Ax[rg + i][k];
            acc[i].x += a.x * wm0.x + a.y * wm1.x + a.z * wm2.x + a.w * wm3.x
                      + c.x * wr0.x + c.y * wr1.x + c.z * wr2.x + c.w * wr3.x;
            acc[i].y += a.x * wm0.y + a.y * wm1.y + a.z * wm2.y + a.w * wm3.y
                      + c.x * wr0.y + c.y * wr1.y + c.z * wr2.y + c.w * wr3.y;
            acc[i].z += a.x * wm0.z + a.y * wm1.z + a.z * wm2.z + a.w * wm3.z
                      + c.x * wr0.z + c.y * wr1.z + c.z * wr2.z + c.w * wr3.z;
            acc[i].w += a.x * wm0.w + a.y * wm1.w + a.z * wm2.w + a.w * wm3.w
                      + c.x * wr0.w + c.y * wr1.w + c.z * wr2.w + c.w * wr3.w;
        }
    }

    float4 bv = *(const float4*)(bias + cg);
#pragma unroll
    for (int i = 0; i < 8; ++i) {
        int gr = row0 + rg + i;
        if (gr < M) {
            float ox = fmaxf(acc[i].x + bv.x, 0.f);
            float oy = fmaxf(acc[i].y + bv.y, 0.f);
            float oz = fmaxf(acc[i].z + bv.z, 0.f);
            float ow = fmaxf(acc[i].w + bv.w, 0.f);
            if (OUT_BF16) {
                uint2 o;
                o.x = f2bf(ox) | (f2bf(oy) << 16);
                o.y = f2bf(oz) | (f2bf(ow) << 16);
                *(uint2*)((unsigned short*)outv + (size_t)gr * D + cg) = o;
            } else {
                float4 o = make_float4(ox, oy, oz, ow);
                *(float4*)((float*)outv + (size_t)gr * D + cg) = o;
            }
        }
    }
}

// ---------------- query = meta @ Wq + bq ----------------

__global__ void k_query(const float* __restrict__ meta, const float* __restrict__ Wq,
                        const float* __restrict__ bq, float* __restrict__ query) {
    int t = blockIdx.x * blockDim.x + threadIdx.x;
    if (t < P_MP * D) {
        int p = t >> 7, c = t & 127;
        float acc = bq[c];
        for (int k = 0; k < D_META; ++k) acc += meta[p * D_META + k] * Wq[k * D + c];
        query[t] = acc;
    }
}

// ---------------- final: per-node softmax over metapaths ----------------

__global__ __launch_bounds__(256) void k_final(const float* __restrict__ emb,
                                               const float* __restrict__ query,
                                               float* __restrict__ out) {
    int wv = (blockIdx.x * blockDim.x + threadIdx.x) >> 6;
    int lane = threadIdx.x & 63;
    if (wv >= NREG) return;
    float2 e[4];
    float sc[4];
#pragma unroll
    for (int p = 0; p < 4; ++p) {
        e[p] = *(const float2*)(emb + ((size_t)p * NREG + wv) * D + lane * 2);
        float2 q = *(const float2*)(query + p * D + lane * 2);
        float d = e[p].x * q.x + e[p].y * q.y;
#pragma unroll
        for (int o = 32; o > 0; o >>= 1) d += __shfl_xor(d, o, 64);
        sc[p] = d * SCALE_F;
    }
    float mx = fmaxf(fmaxf(sc[0], sc[1]), fmaxf(sc[2], sc[3]));
    float w[4], sum = 0.f;
#pragma unroll
    for (int p = 0; p < 4; ++p) { w[p] = __expf(sc[p] - mx); sum += w[p]; }
    float inv = 1.f / sum;
    float ox = 0.f, oy = 0.f;
#pragma unroll
    for (int p = 0; p < 4; ++p) { ox += w[p] * inv * e[p].x; oy += w[p] * inv * e[p].y; }
    float2 o; o.x = ox; o.y = oy;
    *(float2*)(out + (size_t)wv * D + lane * 2) = o;
}

// ---------------- launch ----------------

extern "C" void kernel_launch(void* const* d_in, const int* in_sizes, int n_in,
                              void* d_out, int out_size, void* d_ws, size_t ws_size,
                              hipStream_t stream) {
    const float* Etab  = (const float*)d_in[0];
    const float* meta  = (const float*)d_in[1];
    const float* Wroot = (const float*)d_in[2];   // [4][2][128][128]
    const float* Wrel  = (const float*)d_in[3];   // [4][2][128][128]
    const float* bvec  = (const float*)d_in[4];   // [4][2][128]
    const float* Wq    = (const float*)d_in[5];   // [64][128]
    const float* bq    = (const float*)d_in[6];   // [128]
    const int* edge_index = (const int*)d_in[7];  // [4][2][1600000]
    const int* eids       = (const int*)d_in[8];  // [4][100000]
    float* out = (float*)d_out;

    char* w = (char*)d_ws;
    unsigned short* x0   = (unsigned short*)w;  w += (size_t)N_NODES * D * 2;  // 25.6 MB
    unsigned short* h1   = (unsigned short*)w;  w += (size_t)N_NODES * D * 2;  // 25.6 MB
    unsigned short* sbuf = (unsigned short*)w;  w += (size_t)N_NODES * D * 2;  // 25.6 MB
    float* emb  = (float*)w;  w += (size_t)P_MP * NREG * D * 4;                // 102.4 MB
    float* query= (float*)w;  w += 512 * 4;
    int* cnt    = (int*)w;    w += (size_t)N_NODES * 4;
    int* offs   = (int*)w;    w += (size_t)(N_NODES + 1) * 4;
    int* cursor = (int*)w;    w += (size_t)N_NODES * 4;
    int* ssrc   = (int*)w;    w += (size_t)N_EDGES * 4;
    int* bsum   = (int*)w;    w += (size_t)SCAN_BLOCKS * 4;
    int* ebsum  = (int*)w;    w += (size_t)SCAN_BLOCKS * 4;

    for (int p = 0; p < P_MP; ++p) {
        const int* src = edge_index + (size_t)p * 2 * N_EDGES;
        const int* dst = src + N_EDGES;
        const int* eid = eids + (size_t)p * N_NODES;

        hipMemsetAsync(cnt, 0, (size_t)N_NODES * 4, stream);
        k_hist<<<(N_EDGES + 255) / 256, 256, 0, stream>>>(dst, cnt);
        k_bsum<<<SCAN_BLOCKS, 256, 0, stream>>>(cnt, bsum);
        k_scan_bsum<<<1, 256, 0, stream>>>(bsum, ebsum);
        k_offs<<<SCAN_BLOCKS, 256, 0, stream>>>(cnt, ebsum, offs, cursor);
        k_scatter<<<(N_EDGES + 255) / 256, 256, 0, stream>>>(src, dst, cursor, ssrc);
        k_gather<<<(N_NODES * 16 + 255) / 256, 256, 0, stream>>>(Etab, eid, x0);

        // layer 1 (M = N_NODES)
        k_spmm<<<(N_NODES * 64 + 255) / 256, 256, 0, stream>>>(x0, offs, cnt, ssrc, sbuf, N_NODES);
        {
            const float* Wm = Wrel  + ((size_t)p * L_SUB + 0) * D * D;
            const float* Wr = Wroot + ((size_t)p * L_SUB + 0) * D * D;
            const float* bb = bvec  + ((size_t)p * L_SUB + 0) * D;
            k_gemm<true><<<(N_NODES + TM - 1) / TM, 256, 0, stream>>>(sbuf, x0, Wm, Wr, bb, h1, N_NODES);
        }
        // layer 2 (only rows < NREG are ever consumed)
        k_spmm<<<(NREG * 64 + 255) / 256, 256, 0, stream>>>(h1, offs, cnt, ssrc, sbuf, NREG);
        {
            const float* Wm = Wrel  + ((size_t)p * L_SUB + 1) * D * D;
            const float* Wr = Wroot + ((size_t)p * L_SUB + 1) * D * D;
            const float* bb = bvec  + ((size_t)p * L_SUB + 1) * D;
            k_gemm<false><<<(NREG + TM - 1) / TM, 256, 0, stream>>>(sbuf, h1, Wm, Wr, bb,
                                                                    emb + (size_t)p * NREG * D, NREG);
        }
    }

    k_query<<<2, 256, 0, stream>>>(meta, Wq, bq, query);
    k_final<<<(NREG * 64 + 255) / 256, 256, 0, stream>>>(emb, query, out);
}

// Round 4
// 1995.314 us; speedup vs baseline: 1.7814x; 1.2705x over previous
//
#include <hip/hip_runtime.h>
#include <hip/hip_bf16.h>

#define N_NODES 100000
#define N_EDGES 1600000
#define E_TBL   200000
#define D       128
#define NREG    50000
#define P_MP    4
#define L_SUB   2
#define D_META  64
#define TM      64
#define SCALE_F 0.08838834764831845f   // 1/sqrt(128)

#define SCAN_CHUNK  512
#define SCAN_BLOCKS ((N_NODES + SCAN_CHUNK - 1) / SCAN_CHUNK)   // 196

// ---------------- bf16 helpers (storage-only precision reduction) ----------------

__device__ __forceinline__ float bf2f(unsigned int u16) {
    union { unsigned int i; float f; } v;
    v.i = u16 << 16;
    return v.f;
}
__device__ __forceinline__ unsigned int f2bf(float f) {
    union { float f; unsigned int i; } v;
    v.f = f;
    return (v.i + 0x7fffu + ((v.i >> 16) & 1u)) >> 16;   // RNE
}

// ---------------- CSR build ----------------

__global__ void k_hist(const int* __restrict__ dst, int* __restrict__ cnt) {
    int e = blockIdx.x * blockDim.x + threadIdx.x;
    if (e < N_EDGES) atomicAdd(&cnt[dst[e]], 1);
}

__global__ __launch_bounds__(256) void k_bsum(const int* __restrict__ cnt,
                                              int* __restrict__ bsum) {
    __shared__ int red[256];
    int b = blockIdx.x, t = threadIdx.x;
    int base = b * SCAN_CHUNK + t;
    int v = 0;
    if (base < N_NODES) v += cnt[base];
    if (base + 256 < N_NODES) v += cnt[base + 256];
    red[t] = v;
    __syncthreads();
    for (int o = 128; o > 0; o >>= 1) {
        if (t < o) red[t] += red[t + o];
        __syncthreads();
    }
    if (t == 0) bsum[b] = red[0];
}

__global__ __launch_bounds__(256) void k_scan_bsum(const int* __restrict__ bsum,
                                                   int* __restrict__ ebsum) {
    __shared__ int sh[256];
    int t = threadIdx.x;
    int v = (t < SCAN_BLOCKS) ? bsum[t] : 0;
    sh[t] = v;
    __syncthreads();
    for (int o = 1; o < 256; o <<= 1) {
        int u = (t >= o) ? sh[t - o] : 0;
        __syncthreads();
        sh[t] += u;
        __syncthreads();
    }
    if (t < SCAN_BLOCKS) ebsum[t] = sh[t] - v;   // exclusive
}

__global__ __launch_bounds__(256) void k_offs(const int* __restrict__ cnt,
                                              const int* __restrict__ ebsum,
                                              int* __restrict__ offs,
                                              int* __restrict__ cursor) {
    __shared__ int pair[256];
    int b = blockIdx.x, t = threadIdx.x;
    int i0 = b * SCAN_CHUNK + 2 * t;
    int i1 = i0 + 1;
    int c0 = (i0 < N_NODES) ? cnt[i0] : 0;
    int c1 = (i1 < N_NODES) ? cnt[i1] : 0;
    int ps = c0 + c1;
    pair[t] = ps;
    __syncthreads();
    for (int o = 1; o < 256; o <<= 1) {
        int u = (t >= o) ? pair[t - o] : 0;
        __syncthreads();
        pair[t] += u;
        __syncthreads();
    }
    int off0 = ebsum[b] + pair[t] - ps;
    if (i0 < N_NODES) { offs[i0] = off0; cursor[i0] = off0; }
    if (i1 < N_NODES) { offs[i1] = off0 + c0; cursor[i1] = off0 + c0; }
    if (b == 0 && t == 0) offs[N_NODES] = N_EDGES;
}

__global__ void k_scatter(const int* __restrict__ src, const int* __restrict__ dst,
                          int* __restrict__ cursor, int* __restrict__ ssrc) {
    int e = blockIdx.x * blockDim.x + threadIdx.x;
    if (e < N_EDGES) {
        int pos = atomicAdd(&cursor[dst[e]], 1);
        ssrc[pos] = src[e];
    }
}

// ---------------- gather x0 = bf16(E[eids]) ----------------

__global__ void k_gather(const float* __restrict__ Etab, const int* __restrict__ eids,
                         unsigned short* __restrict__ x0) {
    int i = blockIdx.x * blockDim.x + threadIdx.x;   // N_NODES * 16 (8 cols each)
    int n = i >> 4, g = i & 15;
    if (n >= N_NODES) return;
    int r = eids[n];
    const float4* srcp = (const float4*)(Etab + (size_t)r * D + g * 8);
    float4 a = srcp[0], b = srcp[1];
    uint4 o;
    o.x = f2bf(a.x) | (f2bf(a.y) << 16);
    o.y = f2bf(a.z) | (f2bf(a.w) << 16);
    o.z = f2bf(b.x) | (f2bf(b.y) << 16);
    o.w = f2bf(b.z) | (f2bf(b.w) << 16);
    *(uint4*)(x0 + (size_t)n * D + g * 8) = o;
}

// ---------------- SpMM (bf16 rows, f32 accumulate, bf16 out) ----------------
// one wave per dst row; 8-way MLP: indices loaded coalesced + shfl-broadcast,
// gathers unrolled 8-wide so 8 loads are in flight per wave.

__global__ __launch_bounds__(256) void k_spmm(const unsigned short* __restrict__ x,
                                              const int* __restrict__ offs,
                                              const int* __restrict__ cnt,
                                              const int* __restrict__ ssrc,
                                              unsigned short* __restrict__ s, int nrows) {
    int wv = (blockIdx.x * blockDim.x + threadIdx.x) >> 6;
    int lane = threadIdx.x & 63;
    if (wv >= nrows) return;
    int e0 = offs[wv], e1 = offs[wv + 1];
    const unsigned int* xb = (const unsigned int*)x;   // 2 bf16 per uint, 64 per row
    float ax = 0.f, ay = 0.f;

    int e = e0;
    while (e < e1) {
        int m = min(64, e1 - e);
        int idx = (lane < m) ? ssrc[e + lane] : 0;     // coalesced index load
        int j = 0;
        for (; j + 8 <= m; j += 8) {
            int s0 = __shfl(idx, j + 0, 64);
            int s1 = __shfl(idx, j + 1, 64);
            int s2 = __shfl(idx, j + 2, 64);
            int s3 = __shfl(idx, j + 3, 64);
            int s4 = __shfl(idx, j + 4, 64);
            int s5 = __shfl(idx, j + 5, 64);
            int s6 = __shfl(idx, j + 6, 64);
            int s7 = __shfl(idx, j + 7, 64);
            unsigned int v0 = xb[(size_t)s0 * 64 + lane];
            unsigned int v1 = xb[(size_t)s1 * 64 + lane];
            unsigned int v2 = xb[(size_t)s2 * 64 + lane];
            unsigned int v3 = xb[(size_t)s3 * 64 + lane];
            unsigned int v4 = xb[(size_t)s4 * 64 + lane];
            unsigned int v5 = xb[(size_t)s5 * 64 + lane];
            unsigned int v6 = xb[(size_t)s6 * 64 + lane];
            unsigned int v7 = xb[(size_t)s7 * 64 + lane];
            ax += bf2f(v0 & 0xffffu) + bf2f(v1 & 0xffffu) + bf2f(v2 & 0xffffu) + bf2f(v3 & 0xffffu)
                + bf2f(v4 & 0xffffu) + bf2f(v5 & 0xffffu) + bf2f(v6 & 0xffffu) + bf2f(v7 & 0xffffu);
            ay += bf2f(v0 >> 16) + bf2f(v1 >> 16) + bf2f(v2 >> 16) + bf2f(v3 >> 16)
                + bf2f(v4 >> 16) + bf2f(v5 >> 16) + bf2f(v6 >> 16) + bf2f(v7 >> 16);
        }
        for (; j < m; ++j) {
            int sj = __shfl(idx, j, 64);
            unsigned int v = xb[(size_t)sj * 64 + lane];
            ax += bf2f(v & 0xffffu);
            ay += bf2f(v >> 16);
        }
        e += m;
    }

    float inv = 1.0f / (float)max(cnt[wv], 1);
    unsigned int o = f2bf(ax * inv) | (f2bf(ay * inv) << 16);
    ((unsigned int*)s)[(size_t)wv * 64 + lane] = o;
}

// ---------------- fused GEMM: out = relu(s @ Wm + x @ Wr + b), f32 math ----------------

template <bool OUT_BF16>
__global__ __launch_bounds__(256) void k_gemm(const unsigned short* __restrict__ s,
                                              const unsigned short* __restrict__ x,
                                              const float* __restrict__ Wm,
                                              const float* __restrict__ Wr,
                                              const float* __restrict__ bias,
                                              void* __restrict__ outv, int M) {
    __shared__ float As[TM][D];
    __shared__ float Ax[TM][D];
    int row0 = blockIdx.x * TM;
    int tid = threadIdx.x;

#pragma unroll
    for (int i = 0; i < 4; ++i) {
        int flat = i * 256 + tid;
        int r = flat >> 4;
        int c8 = (flat & 15) * 8;
        int gr = row0 + r;
        uint4 vs = make_uint4(0, 0, 0, 0), vx = vs;
        if (gr < M) {
            vs = *(const uint4*)(s + (size_t)gr * D + c8);
            vx = *(const uint4*)(x + (size_t)gr * D + c8);
        }
        As[r][c8 + 0] = bf2f(vs.x & 0xffffu); As[r][c8 + 1] = bf2f(vs.x >> 16);
        As[r][c8 + 2] = bf2f(vs.y & 0xffffu); As[r][c8 + 3] = bf2f(vs.y >> 16);
        As[r][c8 + 4] = bf2f(vs.z & 0xffffu); As[r][c8 + 5] = bf2f(vs.z >> 16);
        As[r][c8 + 6] = bf2f(vs.w & 0xffffu); As[r][c8 + 7] = bf2f(vs.w >> 16);
        Ax[r][c8 + 0] = bf2f(vx.x & 0xffffu); Ax[r][c8 + 1] = bf2f(vx.x >> 16);
        Ax[r][c8 + 2] = bf2f(vx.y & 0xffffu); Ax[r][c8 + 3] = bf2f(vx.y >> 16);
        Ax[r][c8 + 4] = bf2f(vx.z & 0xffffu); Ax[r][c8 + 5] = bf2f(vx.z >> 16);
        Ax[r][c8 + 6] = bf2f(vx.w & 0xffffu); Ax[r][c8 + 7] = bf2f(vx.w >> 16);
    }
    __syncthreads();

    int cg = (tid & 31) * 4;
    int rg = (tid >> 5) * 8;
    float4 acc[8];
#pragma unroll
    for (int i = 0; i < 8; ++i) acc[i] = make_float4(0, 0, 0, 0);

    for (int k = 0; k < D; k += 4) {
        float4 wm0 = *(const float4*)(Wm + (size_t)(k + 0) * D + cg);
        float4 wm1 = *(const float4*)(Wm + (size_t)(k + 1) * D + cg);
        float4 wm2 = *(const float4*)(Wm + (size_t)(k + 2) * D + cg);
        float4 wm3 = *(const float4*)(Wm + (size_t)(k + 3) * D + cg);
        float4 wr0 = *(const float4*)(Wr + (size_t)(k + 0) * D + cg);
        float4 wr1 = *(const float4*)(Wr + (size_t)(k + 1) * D + cg);
        float4 wr2 = *(const float4*)(Wr + (size_t)(k + 2) * D + cg);
        float4 wr3 = *(const float4*)(Wr + (size_t)(k + 3) * D + cg);
#pragma unroll
        for (int i = 0; i < 8; ++i) {
            float4 a = *(const float4*)&As[rg + i][k];
            float4 c = *(const float4*)&Ax[rg + i][k];
            acc[i].x += a.x * wm0.x + a.y * wm1.x + a.z * wm2.x + a.w * wm3.x
                      + c.x * wr0.x + c.y * wr1.x + c.z * wr2.x + c.w * wr3.x;
            acc[i].y += a.x * wm0.y + a.y * wm1.y + a.z * wm2.y + a.w * wm3.y
                      + c.x * wr0.y + c.y * wr1.y + c.z * wr2.y + c.w * wr3.y;
            acc[i].z += a.x * wm0.z + a.y * wm1.z + a.z * wm2.z + a.w * wm3.z
                      + c.x * wr0.z + c.y * wr1.z + c.z * wr2.z + c.w * wr3.z;
            acc[i].w += a.x * wm0.w + a.y * wm1.w + a.z * wm2.w + a.w * wm3.w
                      + c.x * wr0.w + c.y * wr1.w + c.z * wr2.w + c.w * wr3.w;
        }
    }

    float4 bv = *(const float4*)(bias + cg);
#pragma unroll
    for (int i = 0; i < 8; ++i) {
        int gr = row0 + rg + i;
        if (gr < M) {
            float ox = fmaxf(acc[i].x + bv.x, 0.f);
            float oy = fmaxf(acc[i].y + bv.y, 0.f);
            float oz = fmaxf(acc[i].z + bv.z, 0.f);
            float ow = fmaxf(acc[i].w + bv.w, 0.f);
            if (OUT_BF16) {
                uint2 o;
                o.x = f2bf(ox) | (f2bf(oy) << 16);
                o.y = f2bf(oz) | (f2bf(ow) << 16);
                *(uint2*)((unsigned short*)outv + (size_t)gr * D + cg) = o;
            } else {
                float4 o = make_float4(ox, oy, oz, ow);
                *(float4*)((float*)outv + (size_t)gr * D + cg) = o;
            }
        }
    }
}

// ---------------- query = meta @ Wq + bq ----------------

__global__ void k_query(const float* __restrict__ meta, const float* __restrict__ Wq,
                        const float* __restrict__ bq, float* __restrict__ query) {
    int t = blockIdx.x * blockDim.x + threadIdx.x;
    if (t < P_MP * D) {
        int p = t >> 7, c = t & 127;
        float acc = bq[c];
        for (int k = 0; k < D_META; ++k) acc += meta[p * D_META + k] * Wq[k * D + c];
        query[t] = acc;
    }
}

// ---------------- final: per-node softmax over metapaths ----------------

__global__ __launch_bounds__(256) void k_final(const float* __restrict__ emb,
                                               const float* __restrict__ query,
                                               float* __restrict__ out) {
    int wv = (blockIdx.x * blockDim.x + threadIdx.x) >> 6;
    int lane = threadIdx.x & 63;
    if (wv >= NREG) return;
    float2 e[4];
    float sc[4];
#pragma unroll
    for (int p = 0; p < 4; ++p) {
        e[p] = *(const float2*)(emb + ((size_t)p * NREG + wv) * D + lane * 2);
        float2 q = *(const float2*)(query + p * D + lane * 2);
        float d = e[p].x * q.x + e[p].y * q.y;
#pragma unroll
        for (int o = 32; o > 0; o >>= 1) d += __shfl_xor(d, o, 64);
        sc[p] = d * SCALE_F;
    }
    float mx = fmaxf(fmaxf(sc[0], sc[1]), fmaxf(sc[2], sc[3]));
    float w[4], sum = 0.f;
#pragma unroll
    for (int p = 0; p < 4; ++p) { w[p] = __expf(sc[p] - mx); sum += w[p]; }
    float inv = 1.f / sum;
    float ox = 0.f, oy = 0.f;
#pragma unroll
    for (int p = 0; p < 4; ++p) { ox += w[p] * inv * e[p].x; oy += w[p] * inv * e[p].y; }
    float2 o; o.x = ox; o.y = oy;
    *(float2*)(out + (size_t)wv * D + lane * 2) = o;
}

// ---------------- launch ----------------

extern "C" void kernel_launch(void* const* d_in, const int* in_sizes, int n_in,
                              void* d_out, int out_size, void* d_ws, size_t ws_size,
                              hipStream_t stream) {
    const float* Etab  = (const float*)d_in[0];
    const float* meta  = (const float*)d_in[1];
    const float* Wroot = (const float*)d_in[2];   // [4][2][128][128]
    const float* Wrel  = (const float*)d_in[3];   // [4][2][128][128]
    const float* bvec  = (const float*)d_in[4];   // [4][2][128]
    const float* Wq    = (const float*)d_in[5];   // [64][128]
    const float* bq    = (const float*)d_in[6];   // [128]
    const int* edge_index = (const int*)d_in[7];  // [4][2][1600000]
    const int* eids       = (const int*)d_in[8];  // [4][100000]
    float* out = (float*)d_out;

    char* w = (char*)d_ws;
    unsigned short* x0   = (unsigned short*)w;  w += (size_t)N_NODES * D * 2;  // 25.6 MB
    unsigned short* h1   = (unsigned short*)w;  w += (size_t)N_NODES * D * 2;  // 25.6 MB
    unsigned short* sbuf = (unsigned short*)w;  w += (size_t)N_NODES * D * 2;  // 25.6 MB
    float* emb  = (float*)w;  w += (size_t)P_MP * NREG * D * 4;                // 102.4 MB
    float* query= (float*)w;  w += 512 * 4;
    int* cnt    = (int*)w;    w += (size_t)N_NODES * 4;
    int* offs   = (int*)w;    w += (size_t)(N_NODES + 1) * 4;
    int* cursor = (int*)w;    w += (size_t)N_NODES * 4;
    int* ssrc   = (int*)w;    w += (size_t)N_EDGES * 4;
    int* bsum   = (int*)w;    w += (size_t)SCAN_BLOCKS * 4;
    int* ebsum  = (int*)w;    w += (size_t)SCAN_BLOCKS * 4;

    for (int p = 0; p < P_MP; ++p) {
        const int* src = edge_index + (size_t)p * 2 * N_EDGES;
        const int* dst = src + N_EDGES;
        const int* eid = eids + (size_t)p * N_NODES;

        hipMemsetAsync(cnt, 0, (size_t)N_NODES * 4, stream);
        k_hist<<<(N_EDGES + 255) / 256, 256, 0, stream>>>(dst, cnt);
        k_bsum<<<SCAN_BLOCKS, 256, 0, stream>>>(cnt, bsum);
        k_scan_bsum<<<1, 256, 0, stream>>>(bsum, ebsum);
        k_offs<<<SCAN_BLOCKS, 256, 0, stream>>>(cnt, ebsum, offs, cursor);
        k_scatter<<<(N_EDGES + 255) / 256, 256, 0, stream>>>(src, dst, cursor, ssrc);
        k_gather<<<(N_NODES * 16 + 255) / 256, 256, 0, stream>>>(Etab, eid, x0);

        // layer 1 (M = N_NODES)
        k_spmm<<<(N_NODES * 64 + 255) / 256, 256, 0, stream>>>(x0, offs, cnt, ssrc, sbuf, N_NODES);
        {
            const float* Wm = Wrel  + ((size_t)p * L_SUB + 0) * D * D;
            const float* Wr = Wroot + ((size_t)p * L_SUB + 0) * D * D;
            const float* bb = bvec  + ((size_t)p * L_SUB + 0) * D;
            k_gemm<true><<<(N_NODES + TM - 1) / TM, 256, 0, stream>>>(sbuf, x0, Wm, Wr, bb, h1, N_NODES);
        }
        // layer 2 (only rows < NREG are ever consumed)
        k_spmm<<<(NREG * 64 + 255) / 256, 256, 0, stream>>>(h1, offs, cnt, ssrc, sbuf, NREG);
        {
            const float* Wm = Wrel  + ((size_t)p * L_SUB + 1) * D * D;
            const float* Wr = Wroot + ((size_t)p * L_SUB + 1) * D * D;
            const float* bb = bvec  + ((size_t)p * L_SUB + 1) * D;
            k_gemm<false><<<(NREG + TM - 1) / TM, 256, 0, stream>>>(sbuf, h1, Wm, Wr, bb,
                                                                    emb + (size_t)p * NREG * D, NREG);
        }
    }

    k_query<<<2, 256, 0, stream>>>(meta, Wq, bq, query);
    k_final<<<(NREG * 64 + 255) / 256, 256, 0, stream>>>(emb, query, out);
}